// Round 7
// baseline (203.330 us; speedup 1.0000x reference)
//
#include <hip/hip_runtime.h>

// CRS rate-and-state model. R -> et*R/(1+c*R) is a Mobius map [[a,0],[c,1]];
// maps compose associatively -> whole T=4096 row is ONE two-level scan:
// one 256-thread block per row, lane owns 16 contiguous steps.
// R7: occupancy fix. R6's dual 16.5KB bounce buffers (34.3KB) capped us at
// 4 blocks/CU (36% occupancy measured) with no pipe >40%. R and N bounces
// don't need to coexist: ONE 18.4KB buffer reused (R -> store -> N -> store)
// doubles resident blocks to 8/CU (2048 thr = 100% cap). Skew is now
// 16B-granular (m + ((m>>5)<<2)) so phase-3/4 LDS writes stay b128-contiguous.
// Store stage keeps R6's per-row phase shift -> 64B-aligned f4 global stores
// (no write-allocate RMW; that was worth 148->139).

#define C_TNSR  0.001f
#define C_TSSR  0.002f
#define C_SIGMA 50.0f
#define C_BIOT  0.3f
#define C_R0    0.0001f
#define C_N0    0.0001f

constexpr int B = 8192;
constexpr int T = 4096;
constexpr int STEPS = 16;          // per lane
constexpr int WAVES = 4;           // 256 threads per block = one row

typedef float f4 __attribute__((ext_vector_type(4)));

// 16B-granular skew: every 32 dwords shift by 4 dwords (1 bank group).
// Keeps any [4a..4a+3] group contiguous & 16B-aligned in LDS.
__device__ __forceinline__ int SIDX(int m) { return m + ((m >> 5) << 2); }

__global__ __launch_bounds__(256, 8)
void crs_row_kernel(const float* __restrict__ params,
                    const float* __restrict__ p,
                    const float* __restrict__ dpdt,
                    const float* __restrict__ dtv,
                    float* __restrict__ Rt,
                    float* __restrict__ Nt)
{
    __shared__ float ls[T + (T >> 5) * 4];   // 4608 floats = 18.0 KB, reused R then N
    __shared__ float sA[WAVES], sC[WAVES], sS[WAVES];

    const int tid  = threadIdx.x;
    const int lane = tid & 63;
    const int wid  = tid >> 6;
    const int b    = blockIdx.x;

    const float mu  = params[b * 3 + 0];
    const float rc  = params[b * 3 + 1];
    const float rf  = params[b * 3 + 2];
    const float eta = 1.0f / rf;
    const float rcS = rc * C_SIGMA;
    const float rcB = rc * C_BIOT;

    const int seg = tid * STEPS;
    const float* __restrict__ prow = p    + (size_t)b * T + seg;
    const float* __restrict__ drow = dpdt + (size_t)b * T + seg;
    const float* __restrict__ trow = dtv  + (size_t)b * T + seg;

    // ---- load this lane's 16 steps (64B-aligned dwordx4, dense) ----
    f4 pv[4], dv[4], tv[4];
#pragma unroll
    for (int q = 0; q < 4; ++q) pv[q] = *(const f4*)(prow + 4 * q);
#pragma unroll
    for (int q = 0; q < 4; ++q) dv[q] = *(const f4*)(drow + 4 * q);
#pragma unroll
    for (int q = 0; q < 4; ++q) tv[q] = *(const f4*)(trow + 4 * q);

    // ---- phase 1: per-lane inclusive Mobius prefixes ----
    float Aj[STEPS], Cj[STEPS], kk[STEPS];
    float A = 1.0f, C = 0.0f;
#pragma unroll
    for (int j = 0; j < STEPS; ++j) {
        float pp = pv[j >> 2][j & 3];
        float dd = dv[j >> 2][j & 3];
        float tt = tv[j >> 2][j & 3];
        float sd   = C_TSSR - mu * (C_TNSR - dd);
        float asig = fmaf(-rcB, pp, rcS);
        float e    = __expf(__fdividef(sd * tt, asig));
        float c    = __fdividef(eta * (e - 1.0f), sd);
        kk[j] = asig * rf;               // asig/eta
        C = fmaf(c, A, C);               // compose step j after (A,C)
        A = A * e;
        Aj[j] = A;
        Cj[j] = C;
    }

    // ---- phase 2a: wave-inclusive scan of (A,C) ----
#pragma unroll
    for (int o = 1; o < 64; o <<= 1) {
        float Ap = __shfl_up(A, (unsigned)o, 64);
        float Cp = __shfl_up(C, (unsigned)o, 64);
        if (lane >= o) { C = fmaf(C, Ap, Cp); A = A * Ap; }
    }
    float Ae = __shfl_up(A, 1u, 64);
    float Ce = __shfl_up(C, 1u, 64);
    if (lane == 0) { Ae = 1.0f; Ce = 0.0f; }

    // ---- phase 2b: cross-wave composition via LDS ----
    if (lane == 63) { sA[wid] = A; sC[wid] = C; }
    __syncthreads();                                   // #1
    float PA = 1.0f, PC = 0.0f;
#pragma unroll
    for (int w = 0; w < WAVES - 1; ++w) {
        if (w < wid) { PC = fmaf(sC[w], PA, PC); PA = sA[w] * PA; }
    }
    float EA = Ae * PA;
    float EC = fmaf(Ce, PA, PC);
    float Rt_ = __fdividef(EA * C_R0, fmaf(EC, C_R0, 1.0f));   // R entering segment

    // ---- phase 3: closed-form R -> LDS, N terms -> regs (den telescopes) ----
    float nn[STEPS];
    float ns = 0.0f;
    float rlPrev = 1.0f;
#pragma unroll
    for (int j = 0; j < STEPS; ++j) {
        float L   = fmaf(Cj[j], Rt_, 1.0f);
        float rlj = __fdividef(1.0f, L);
        ls[SIDX(seg + j)] = (Aj[j] * Rt_) * rlj;
        float den = L * rlPrev;                        // == 1 + c_j*R_{j-1}
        ns += kk[j] * __logf(den);
        nn[j] = ns;
        rlPrev = rlj;
    }

    // ---- wave prefix sum of per-lane N totals (overlap with R bounce) ----
    float S = ns;
#pragma unroll
    for (int o = 1; o < 64; o <<= 1) {
        float Sp = __shfl_up(S, (unsigned)o, 64);
        if (lane >= o) S += Sp;
    }
    if (lane == 63) sS[wid] = S;
    __syncthreads();                                   // #2: R in LDS, sS ready

    // ---- store-stage geometry ----
    const size_t g0 = (size_t)b * (T + 1) + 1;         // dword index of step 0
    const int s  = (int)((16 - (g0 & 15)) & 15);       // shift to 64B boundary
    const int tl = (T - s) & 3;                        // tail dwords
    const int bodyEnd = T - tl;

    // ---- R store stage (64B-aligned f4 body) ----
    if (tid == 0) Rt[g0 - 1] = C_R0;
    if (tid < s)  Rt[g0 + tid] = ls[SIDX(tid)];
    if (tid < tl) { int m = bodyEnd + tid; Rt[g0 + m] = ls[SIDX(m)]; }
#pragma unroll
    for (int q = 0; q < 4; ++q) {
        int m0 = s + q * 1024 + tid * 4;
        if (m0 + 4 <= bodyEnd) {
            f4 r;
#pragma unroll
            for (int c = 0; c < 4; ++c) r[c] = ls[SIDX(m0 + c)];
            *(f4*)(Rt + g0 + m0) = r;
        }
    }
    __syncthreads();                                   // #3: R reads done

    // ---- N values -> LDS (b128 writes) ----
    float PS = C_N0;
#pragma unroll
    for (int w = 0; w < WAVES - 1; ++w) {
        if (w < wid) PS += sS[w];
    }
    float base = PS + (S - ns);
#pragma unroll
    for (int q = 0; q < 4; ++q) {
        f4 n;
#pragma unroll
        for (int c = 0; c < 4; ++c) n[c] = base + nn[4 * q + c];
        *(f4*)(ls + SIDX(seg + 4 * q)) = n;
    }
    __syncthreads();                                   // #4: N in LDS

    // ---- N store stage ----
    if (tid == 0) Nt[g0 - 1] = C_N0;
    if (tid < s)  Nt[g0 + tid] = ls[SIDX(tid)];
    if (tid < tl) { int m = bodyEnd + tid; Nt[g0 + m] = ls[SIDX(m)]; }
#pragma unroll
    for (int q = 0; q < 4; ++q) {
        int m0 = s + q * 1024 + tid * 4;
        if (m0 + 4 <= bodyEnd) {
            f4 n;
#pragma unroll
            for (int c = 0; c < 4; ++c) n[c] = ls[SIDX(m0 + c)];
            *(f4*)(Nt + g0 + m0) = n;
        }
    }
}

extern "C" void kernel_launch(void* const* d_in, const int* in_sizes, int n_in,
                              void* d_out, int out_size, void* d_ws, size_t ws_size,
                              hipStream_t stream)
{
    const float* params = (const float*)d_in[0];
    const float* p      = (const float*)d_in[1];
    const float* dpdt   = (const float*)d_in[2];
    const float* dtv    = (const float*)d_in[3];

    float* Rt = (float*)d_out;                       // B*(T+1)
    float* Nt = (float*)d_out + (size_t)B * (T + 1); // B*(T+1)

    crs_row_kernel<<<B, 256, 0, stream>>>(params, p, dpdt, dtv, Rt, Nt);
}

// Round 8
// 149.787 us; speedup vs baseline: 1.3575x; 1.3575x over previous
//
#include <hip/hip_runtime.h>

// CRS rate-and-state model. R -> et*R/(1+c*R) is a Mobius map [[a,0],[c,1]];
// maps compose associatively -> whole T=4096 row is ONE two-level scan:
// one 256-thread block per row, lane owns 16 contiguous steps.
// R8 = R6 (best: 139us) + single reused bounce buffer.
//  - R7's launch_bounds(256,8) caused scratch spills (VGPR 32, FETCH +230MB)
//    -> keep (256,4), VGPR cap 128 (R6 compiled to 52, no spill).
//  - R7's 16B-granular skew was 8-way bank conflicting on phase-3 writes
//    -> keep R6's dword skew m+(m>>5) (2-way = free; 1.7M confl cycles).
//  - Single ~16.9KB LDS buffer reused (R -> store -> N -> store): LDS cap
//    moves 4 -> 8 blocks/CU (thread-capped), occupancy ceiling 50% -> 100%.
// Store stage keeps the per-row phase shift -> 64B-aligned f4 global stores
// (write-allocate RMW elimination was the 148->139 win).

#define C_TNSR  0.001f
#define C_TSSR  0.002f
#define C_SIGMA 50.0f
#define C_BIOT  0.3f
#define C_R0    0.0001f
#define C_N0    0.0001f

constexpr int B = 8192;
constexpr int T = 4096;
constexpr int STEPS = 16;          // per lane
constexpr int WAVES = 4;           // 256 threads per block = one row

typedef float f4 __attribute__((ext_vector_type(4)));

// dword-granular skew: 2-way max bank aliasing on all our patterns (R6-verified)
__device__ __forceinline__ int SIDX(int m) { return m + (m >> 5); }

__global__ __launch_bounds__(256, 4)
void crs_row_kernel(const float* __restrict__ params,
                    const float* __restrict__ p,
                    const float* __restrict__ dpdt,
                    const float* __restrict__ dtv,
                    float* __restrict__ Rt,
                    float* __restrict__ Nt)
{
    __shared__ float ls[T + T / 32];     // 4224 floats = 16.5 KB, reused R then N
    __shared__ float sA[WAVES], sC[WAVES], sS[WAVES];

    const int tid  = threadIdx.x;
    const int lane = tid & 63;
    const int wid  = tid >> 6;
    const int b    = blockIdx.x;

    const float mu  = params[b * 3 + 0];
    const float rc  = params[b * 3 + 1];
    const float rf  = params[b * 3 + 2];
    const float eta = 1.0f / rf;
    const float rcS = rc * C_SIGMA;
    const float rcB = rc * C_BIOT;

    const int seg = tid * STEPS;
    const float* __restrict__ prow = p    + (size_t)b * T + seg;
    const float* __restrict__ drow = dpdt + (size_t)b * T + seg;
    const float* __restrict__ trow = dtv  + (size_t)b * T + seg;

    // ---- load this lane's 16 steps (64B-aligned dwordx4, dense) ----
    f4 pv[4], dv[4], tv[4];
#pragma unroll
    for (int q = 0; q < 4; ++q) pv[q] = *(const f4*)(prow + 4 * q);
#pragma unroll
    for (int q = 0; q < 4; ++q) dv[q] = *(const f4*)(drow + 4 * q);
#pragma unroll
    for (int q = 0; q < 4; ++q) tv[q] = *(const f4*)(trow + 4 * q);

    // ---- phase 1: per-lane inclusive Mobius prefixes ----
    float Aj[STEPS], Cj[STEPS], kk[STEPS];
    float A = 1.0f, C = 0.0f;
#pragma unroll
    for (int j = 0; j < STEPS; ++j) {
        float pp = pv[j >> 2][j & 3];
        float dd = dv[j >> 2][j & 3];
        float tt = tv[j >> 2][j & 3];
        float sd   = C_TSSR - mu * (C_TNSR - dd);
        float asig = fmaf(-rcB, pp, rcS);
        float e    = __expf(__fdividef(sd * tt, asig));
        float c    = __fdividef(eta * (e - 1.0f), sd);
        kk[j] = asig * rf;               // asig/eta
        C = fmaf(c, A, C);               // compose step j after (A,C)
        A = A * e;
        Aj[j] = A;
        Cj[j] = C;
    }

    // ---- phase 2a: wave-inclusive scan of (A,C) ----
#pragma unroll
    for (int o = 1; o < 64; o <<= 1) {
        float Ap = __shfl_up(A, (unsigned)o, 64);
        float Cp = __shfl_up(C, (unsigned)o, 64);
        if (lane >= o) { C = fmaf(C, Ap, Cp); A = A * Ap; }
    }
    float Ae = __shfl_up(A, 1u, 64);
    float Ce = __shfl_up(C, 1u, 64);
    if (lane == 0) { Ae = 1.0f; Ce = 0.0f; }

    // ---- phase 2b: cross-wave composition via LDS ----
    if (lane == 63) { sA[wid] = A; sC[wid] = C; }
    __syncthreads();                                   // #1
    float PA = 1.0f, PC = 0.0f;
#pragma unroll
    for (int w = 0; w < WAVES - 1; ++w) {
        if (w < wid) { PC = fmaf(sC[w], PA, PC); PA = sA[w] * PA; }
    }
    float EA = Ae * PA;
    float EC = fmaf(Ce, PA, PC);
    float Rt_ = __fdividef(EA * C_R0, fmaf(EC, C_R0, 1.0f));   // R entering segment

    // ---- phase 3: closed-form R -> LDS, N terms -> regs (den telescopes) ----
    float nn[STEPS];
    float ns = 0.0f;
    float rlPrev = 1.0f;
#pragma unroll
    for (int j = 0; j < STEPS; ++j) {
        float L   = fmaf(Cj[j], Rt_, 1.0f);
        float rlj = __fdividef(1.0f, L);
        ls[SIDX(seg + j)] = (Aj[j] * Rt_) * rlj;
        float den = L * rlPrev;                        // == 1 + c_j*R_{j-1}
        ns += kk[j] * __logf(den);
        nn[j] = ns;
        rlPrev = rlj;
    }

    // ---- wave prefix sum of per-lane N totals ----
    float S = ns;
#pragma unroll
    for (int o = 1; o < 64; o <<= 1) {
        float Sp = __shfl_up(S, (unsigned)o, 64);
        if (lane >= o) S += Sp;
    }
    if (lane == 63) sS[wid] = S;
    __syncthreads();                                   // #2: R in LDS, sS ready

    // ---- store-stage geometry ----
    const size_t g0 = (size_t)b * (T + 1) + 1;         // dword index of step 0
    const int s  = (int)((16 - (g0 & 15)) & 15);       // shift to 64B boundary
    const int tl = (T - s) & 3;                        // tail dwords
    const int bodyEnd = T - tl;

    // ---- R store stage (64B-aligned f4 body) ----
    if (tid == 0) Rt[g0 - 1] = C_R0;
    if (tid < s)  Rt[g0 + tid] = ls[SIDX(tid)];
    if (tid < tl) { int m = bodyEnd + tid; Rt[g0 + m] = ls[SIDX(m)]; }
#pragma unroll
    for (int q = 0; q < 4; ++q) {
        int m0 = s + q * 1024 + tid * 4;
        if (m0 + 4 <= bodyEnd) {
            f4 r;
#pragma unroll
            for (int c = 0; c < 4; ++c) r[c] = ls[SIDX(m0 + c)];
            *(f4*)(Rt + g0 + m0) = r;
        }
    }
    __syncthreads();                                   // #3: R gather done

    // ---- N values -> LDS ----
    float PS = C_N0;
#pragma unroll
    for (int w = 0; w < WAVES - 1; ++w) {
        if (w < wid) PS += sS[w];
    }
    float base = PS + (S - ns);
#pragma unroll
    for (int j = 0; j < STEPS; ++j)
        ls[SIDX(seg + j)] = base + nn[j];
    __syncthreads();                                   // #4: N in LDS

    // ---- N store stage ----
    if (tid == 0) Nt[g0 - 1] = C_N0;
    if (tid < s)  Nt[g0 + tid] = ls[SIDX(tid)];
    if (tid < tl) { int m = bodyEnd + tid; Nt[g0 + m] = ls[SIDX(m)]; }
#pragma unroll
    for (int q = 0; q < 4; ++q) {
        int m0 = s + q * 1024 + tid * 4;
        if (m0 + 4 <= bodyEnd) {
            f4 n;
#pragma unroll
            for (int c = 0; c < 4; ++c) n[c] = ls[SIDX(m0 + c)];
            *(f4*)(Nt + g0 + m0) = n;
        }
    }
}

extern "C" void kernel_launch(void* const* d_in, const int* in_sizes, int n_in,
                              void* d_out, int out_size, void* d_ws, size_t ws_size,
                              hipStream_t stream)
{
    const float* params = (const float*)d_in[0];
    const float* p      = (const float*)d_in[1];
    const float* dpdt   = (const float*)d_in[2];
    const float* dtv    = (const float*)d_in[3];

    float* Rt = (float*)d_out;                       // B*(T+1)
    float* Nt = (float*)d_out + (size_t)B * (T + 1); // B*(T+1)

    crs_row_kernel<<<B, 256, 0, stream>>>(params, p, dpdt, dtv, Rt, Nt);
}

// Round 9
// 128.293 us; speedup vs baseline: 1.5849x; 1.1675x over previous
//
#include <hip/hip_runtime.h>

// CRS rate-and-state model. R -> et*R/(1+c*R) is a Mobius map [[a,0],[c,1]];
// maps compose associatively -> whole T=4096 row is ONE two-level scan:
// one 256-thread block per row, lane owns 16 contiguous steps.
// R9 = R6 (best structure: 139us; dual LDS bounce, parallel R/N store stages)
//      + NONTEMPORAL output stores.
// Rationale: occupancy is not binding (R8: 62% occ was SLOWER than R6's 36%);
// FETCH_SIZE (~300-330MB vs 402MB input) shows L3 already retains ~25% of the
// replay-invariant inputs; the 268MB of write-once output was allocating in
// L3 and thrashing that retention. nt stores = evict-first, L3 stays input-only.

#define C_TNSR  0.001f
#define C_TSSR  0.002f
#define C_SIGMA 50.0f
#define C_BIOT  0.3f
#define C_R0    0.0001f
#define C_N0    0.0001f

constexpr int B = 8192;
constexpr int T = 4096;
constexpr int STEPS = 16;          // per lane
constexpr int WAVES = 4;           // 256 threads per block = one row

typedef float f4 __attribute__((ext_vector_type(4)));

__device__ __forceinline__ int SIDX(int m) { return m + (m >> 5); }

__global__ __launch_bounds__(256, 4)
void crs_row_kernel(const float* __restrict__ params,
                    const float* __restrict__ p,
                    const float* __restrict__ dpdt,
                    const float* __restrict__ dtv,
                    float* __restrict__ Rt,
                    float* __restrict__ Nt)
{
    __shared__ float lsR[T + T / 32];   // 16.5 KB, skew-indexed
    __shared__ float lsN[T + T / 32];
    __shared__ float sA[WAVES], sC[WAVES], sS[WAVES];

    const int tid  = threadIdx.x;
    const int lane = tid & 63;
    const int wid  = tid >> 6;
    const int b    = blockIdx.x;

    const float mu  = params[b * 3 + 0];
    const float rc  = params[b * 3 + 1];
    const float rf  = params[b * 3 + 2];
    const float eta = 1.0f / rf;
    const float rcS = rc * C_SIGMA;
    const float rcB = rc * C_BIOT;

    const int seg = tid * STEPS;
    const float* __restrict__ prow = p    + (size_t)b * T + seg;
    const float* __restrict__ drow = dpdt + (size_t)b * T + seg;
    const float* __restrict__ trow = dtv  + (size_t)b * T + seg;

    // ---- load this lane's 16 steps (64B-aligned dwordx4, dense) ----
    f4 pv[4], dv[4], tv[4];
#pragma unroll
    for (int q = 0; q < 4; ++q) pv[q] = *(const f4*)(prow + 4 * q);
#pragma unroll
    for (int q = 0; q < 4; ++q) dv[q] = *(const f4*)(drow + 4 * q);
#pragma unroll
    for (int q = 0; q < 4; ++q) tv[q] = *(const f4*)(trow + 4 * q);

    // ---- phase 1: per-lane inclusive Mobius prefixes ----
    float Aj[STEPS], Cj[STEPS], kk[STEPS];
    float A = 1.0f, C = 0.0f;
#pragma unroll
    for (int j = 0; j < STEPS; ++j) {
        float pp = pv[j >> 2][j & 3];
        float dd = dv[j >> 2][j & 3];
        float tt = tv[j >> 2][j & 3];
        float sd   = C_TSSR - mu * (C_TNSR - dd);
        float asig = fmaf(-rcB, pp, rcS);
        float e    = __expf(__fdividef(sd * tt, asig));
        float c    = __fdividef(eta * (e - 1.0f), sd);
        kk[j] = asig * rf;               // asig/eta
        C = fmaf(c, A, C);               // compose step j after (A,C)
        A = A * e;
        Aj[j] = A;
        Cj[j] = C;
    }

    // ---- phase 2a: wave-inclusive scan of (A,C) ----
#pragma unroll
    for (int o = 1; o < 64; o <<= 1) {
        float Ap = __shfl_up(A, (unsigned)o, 64);
        float Cp = __shfl_up(C, (unsigned)o, 64);
        if (lane >= o) { C = fmaf(C, Ap, Cp); A = A * Ap; }
    }
    float Ae = __shfl_up(A, 1u, 64);
    float Ce = __shfl_up(C, 1u, 64);
    if (lane == 0) { Ae = 1.0f; Ce = 0.0f; }

    // ---- phase 2b: cross-wave composition via LDS ----
    if (lane == 63) { sA[wid] = A; sC[wid] = C; }
    __syncthreads();
    float PA = 1.0f, PC = 0.0f;
#pragma unroll
    for (int w = 0; w < WAVES - 1; ++w) {
        if (w < wid) { PC = fmaf(sC[w], PA, PC); PA = sA[w] * PA; }
    }
    float EA = Ae * PA;
    float EC = fmaf(Ce, PA, PC);
    float Rt_ = __fdividef(EA * C_R0, fmaf(EC, C_R0, 1.0f));   // R entering segment

    // ---- phase 3: closed-form outputs; den telescopes: den_j = L_j * rl_{j-1} ----
    float nn[STEPS];
    float ns = 0.0f;
    float rlPrev = 1.0f;
#pragma unroll
    for (int j = 0; j < STEPS; ++j) {
        float L   = fmaf(Cj[j], Rt_, 1.0f);
        float rlj = __fdividef(1.0f, L);
        lsR[SIDX(seg + j)] = (Aj[j] * Rt_) * rlj;
        float den = L * rlPrev;                        // == 1 + c_j*R_{j-1}
        ns += kk[j] * __logf(den);
        nn[j] = ns;
        rlPrev = rlj;
    }

    // ---- phase 4: two-level prefix sum of per-lane N totals ----
    float S = ns;
#pragma unroll
    for (int o = 1; o < 64; o <<= 1) {
        float Sp = __shfl_up(S, (unsigned)o, 64);
        if (lane >= o) S += Sp;
    }
    if (lane == 63) sS[wid] = S;
    __syncthreads();
    float PS = C_N0;
#pragma unroll
    for (int w = 0; w < WAVES - 1; ++w) {
        if (w < wid) PS += sS[w];
    }
    float base = PS + (S - ns);
#pragma unroll
    for (int j = 0; j < STEPS; ++j)
        lsN[SIDX(seg + j)] = base + nn[j];

    __syncthreads();

    // ---- aligned store stage (all global stores NONTEMPORAL) ----
    const size_t g0 = (size_t)b * (T + 1) + 1;         // dword index of step 0
    const int s  = (int)((16 - (g0 & 15)) & 15);       // shift to 64B boundary
    const int tl = (T - s) & 3;                        // tail dwords
    const int bodyEnd = T - tl;

    if (tid == 0) {
        __builtin_nontemporal_store(C_R0, Rt + g0 - 1);
        __builtin_nontemporal_store(C_N0, Nt + g0 - 1);
    }
    if (tid < s) {
        __builtin_nontemporal_store(lsR[SIDX(tid)], Rt + g0 + tid);
        __builtin_nontemporal_store(lsN[SIDX(tid)], Nt + g0 + tid);
    }
    if (tid < tl) {
        int m = bodyEnd + tid;
        __builtin_nontemporal_store(lsR[SIDX(m)], Rt + g0 + m);
        __builtin_nontemporal_store(lsN[SIDX(m)], Nt + g0 + m);
    }

#pragma unroll
    for (int q = 0; q < 4; ++q) {                      // body: 64B-aligned f4
        int m0 = s + q * 1024 + tid * 4;
        if (m0 + 4 <= bodyEnd) {
            f4 r, n;
#pragma unroll
            for (int c = 0; c < 4; ++c) {
                r[c] = lsR[SIDX(m0 + c)];
                n[c] = lsN[SIDX(m0 + c)];
            }
            __builtin_nontemporal_store(r, (f4*)(Rt + g0 + m0));
            __builtin_nontemporal_store(n, (f4*)(Nt + g0 + m0));
        }
    }
}

extern "C" void kernel_launch(void* const* d_in, const int* in_sizes, int n_in,
                              void* d_out, int out_size, void* d_ws, size_t ws_size,
                              hipStream_t stream)
{
    const float* params = (const float*)d_in[0];
    const float* p      = (const float*)d_in[1];
    const float* dpdt   = (const float*)d_in[2];
    const float* dtv    = (const float*)d_in[3];

    float* Rt = (float*)d_out;                       // B*(T+1)
    float* Nt = (float*)d_out + (size_t)B * (T + 1); // B*(T+1)

    crs_row_kernel<<<B, 256, 0, stream>>>(params, p, dpdt, dtv, Rt, Nt);
}